// Round 22
// baseline (77.354 us; speedup 1.0000x reference)
//
#include <hip/hip_runtime.h>
#include <math.h>

#define B_ 8
#define N_ 2048
#define H_ 256

typedef double d4 __attribute__((ext_vector_type(4)));

// One-shot: W1T[k][o] = W1[o][k] (f32). Consecutive lanes read consecutive
// o -> coalesced (r19 lesson: lane coalescing beats per-lane load width).
__global__ __launch_bounds__(256)
void transpose_w1(const float* __restrict__ W1, float* __restrict__ W1T) {
    W1T[(size_t)blockIdx.x * H_ + threadIdx.x] =
        W1[(size_t)threadIdx.x * H_ + blockIdx.x];
}

// In-kernel probe of the v_mfma_f64_16x16x4_f64 lane mapping (~200 cy).
// Rounds 15-18 proved one of vars 1-4 matches on this chip.
__device__ __forceinline__ int self_probe_var() {
    const int l = threadIdx.x & 63;
    d4 z = {0.0, 0.0, 0.0, 0.0};
    d4 r1 = __builtin_amdgcn_mfma_f64_16x16x4f64((double)(l + 1), 1.0, z, 0, 0, 0);
    d4 r2 = __builtin_amdgcn_mfma_f64_16x16x4f64(1.0, (double)(l + 1), z, 0, 0, 0);
    d4 r3 = __builtin_amdgcn_mfma_f64_16x16x4f64((double)(l & 15), 1.0, z, 0, 0, 0);
    const double pw0 = __shfl(r1[0], 0, 64);
    const double pw1 = __shfl(r2[0], 0, 64);
    const double pw2 = __shfl(r3[0], 1, 64);
    const double pw3 = __shfl(r3[2], 16, 64);
    const double pw4 = __shfl(r2[2], 16, 64);
    if (pw0 != 100.0 || pw1 != 100.0) return 0;
    if (pw2 == 0.0 && pw3 == 24.0)  return 1;   // row=4g+v, col=a15
    if (pw2 == 0.0 && pw3 == 36.0)  return 3;   // row=g+4v, col=a15
    if (pw2 == 4.0 && pw4 == 124.0) return 2;   // row=a15,  col=4g+v
    if (pw2 == 4.0 && pw4 == 136.0) return 4;   // row=a15,  col=g+4v
    return 0;
}

// MFMA s-kernel, round-22: first clean 4-waves/SIMD config.
// 16 rows/block, grid 1024 (4 blocks/CU target), 4 waves; wave = full-K
// 64-o strip (4 o-tiles), 1 m-tile -> acc = 32 VGPR, slim buffers (~80
// total). h staged in LDS TRANSPOSED hs_t[k][row] (+1 pad): A-read
// hs_t[k][a15] has consecutive lanes at consecutive addresses ->
// conflict-free (r21's hs[a15][k] was a 16-way bank conflict). B =
// coalesced scalar loads from L2-resident W1T, one 8-k chunk prefetch.
// Hypothesis under test: r17/r20/r21 all ran ~2 waves/SIMD and plateaued
// at ~2x the 27.3us pipe floor; 4 waves/SIMD should halve the gap.
__global__ __launch_bounds__(256)
__attribute__((amdgpu_waves_per_eu(2, 4)))
void s_mfma_uni(const float* __restrict__ hp, const float* __restrict__ W1T,
                const float* __restrict__ b1, const float* __restrict__ w2,
                double* __restrict__ s_out) {
    const int var = self_probe_var();
    if (var == 0) return;                       // VALU fallback does the work
    __shared__ float hs_t[H_][17];              // [k][row], 17.4 KB, padded
    __shared__ double spart[4][16];
    const int t = threadIdx.x;
    const int lane = t & 63;
    const int wave = __builtin_amdgcn_readfirstlane(t >> 6);
    const int a15 = lane & 15, g = lane >> 4;
    const int m0 = blockIdx.x * 16;
    const int oc = wave * 64;

    // Stage h tile transposed: thread t = k-column, row i. Global coalesced;
    // LDS write addr = t*17 + i -> stride 17 across lanes = conflict-free.
    #pragma unroll
    for (int i = 0; i < 16; ++i)
        hs_t[t][i] = hp[(size_t)(m0 + i) * H_ + t];
    __syncthreads();

    // B: W1T[k + g][oc + ot*16 + a15] — consecutive a15 lanes -> consecutive
    // floats (coalesced); g picks the k-row.
    const float* bp = W1T + (size_t)g * H_ + oc + a15;

    d4 acc[4];
    #pragma unroll
    for (int ot = 0; ot < 4; ++ot) acc[ot] = (d4){0.0, 0.0, 0.0, 0.0};

    float ac[2], an[2];        // A: [half], hs_t[kc + 4*half + g][a15]
    float bcv[8], bnv[8];      // B: [half*4 + ot]
    ac[0] = hs_t[g][a15];
    ac[1] = hs_t[4 + g][a15];
    #pragma unroll
    for (int ot = 0; ot < 4; ++ot) {
        bcv[ot]     = bp[ot * 16];
        bcv[4 + ot] = bp[4 * H_ + ot * 16];
    }

    for (int kc = 0; kc < H_; kc += 8) {
        const int kn = (kc + 8 < H_) ? (kc + 8) : 0;      // guarded prefetch
        an[0] = hs_t[kn + g][a15];
        an[1] = hs_t[kn + 4 + g][a15];
        #pragma unroll
        for (int ot = 0; ot < 4; ++ot) {
            bnv[ot]     = bp[(size_t)kn * H_ + ot * 16];
            bnv[4 + ot] = bp[(size_t)(kn + 4) * H_ + ot * 16];
        }
        {   // k half 0 (k = kc..kc+3)
            const double a0 = (double)ac[0];
            #pragma unroll
            for (int ot = 0; ot < 4; ++ot)
                acc[ot] = __builtin_amdgcn_mfma_f64_16x16x4f64(
                    a0, (double)bcv[ot], acc[ot], 0, 0, 0);
        }
        {   // k half 1 (k = kc+4..kc+7)
            const double a1 = (double)ac[1];
            #pragma unroll
            for (int ot = 0; ot < 4; ++ot)
                acc[ot] = __builtin_amdgcn_mfma_f64_16x16x4f64(
                    a1, (double)bcv[4 + ot], acc[ot], 0, 0, 0);
        }
        ac[0] = an[0]; ac[1] = an[1];
        #pragma unroll
        for (int q = 0; q < 8; ++q) bcv[q] = bnv[q];
    }

    if (var == 1 || var == 3) {
        // col = a15 (per lane); row = 4g+v (var 1) or g+4v (var 3).
        double psum[4] = {0.0, 0.0, 0.0, 0.0};
        #pragma unroll
        for (int ot = 0; ot < 4; ++ot) {
            const int o = oc + ot * 16 + a15;
            const double bb = (double)b1[o];
            const double ww = (double)w2[o];
            #pragma unroll
            for (int v = 0; v < 4; ++v) {
                const double u = acc[ot][v] + bb;
                psum[v] += ww * (u / (1.0 + exp(-u)));
            }
        }
        #pragma unroll
        for (int v = 0; v < 4; ++v) {
            double x = psum[v];
            x += __shfl_xor(x, 1, 64);
            x += __shfl_xor(x, 2, 64);
            x += __shfl_xor(x, 4, 64);
            x += __shfl_xor(x, 8, 64);
            psum[v] = x;
        }
        if (a15 == 0) {
            #pragma unroll
            for (int v = 0; v < 4; ++v) {
                const int row = (var == 1) ? (4 * g + v) : (g + 4 * v);
                spart[wave][row] = psum[v];
            }
        }
    } else {
        // row = a15 (per lane); col = 4g+v (var 2) or g+4v (var 4).
        double ps = 0.0;
        #pragma unroll
        for (int ot = 0; ot < 4; ++ot)
            #pragma unroll
            for (int v = 0; v < 4; ++v) {
                const int cv = (var == 2) ? (4 * g + v) : (g + 4 * v);
                const int o = oc + ot * 16 + cv;
                const double u = acc[ot][v] + (double)b1[o];
                ps += (double)w2[o] * (u / (1.0 + exp(-u)));
            }
        ps += __shfl_xor(ps, 16, 64);
        ps += __shfl_xor(ps, 32, 64);
        if (g == 0) spart[wave][a15] = ps;
    }
    __syncthreads();
    if (t < 16)
        s_out[m0 + t] = spart[0][t] + spart[1][t] + spart[2][t] + spart[3][t];
}

// VALU fallback (round-11 verified body, W1T layout): only if probe var==0.
__global__ __launch_bounds__(256)
__attribute__((amdgpu_waves_per_eu(2, 4)))
void s_valu_kernel(const float* __restrict__ hp, const float* __restrict__ W1T,
                   const float* __restrict__ b1, const float* __restrict__ w2,
                   double* __restrict__ s_out) {
    if (self_probe_var() != 0) return;
    const int t = threadIdx.x;
    const int lane = t & 63;
    const int wave = __builtin_amdgcn_readfirstlane(t >> 6);
    const int m0 = blockIdx.x * 16 + wave * 4;
    const int o0 = lane * 4;
    const float* hr = hp + (size_t)m0 * H_;
    const float* wp = W1T + o0;

    double acc[4][4];
    #pragma unroll
    for (int j = 0; j < 4; ++j)
        #pragma unroll
        for (int r = 0; r < 4; ++r) acc[j][r] = 0.0;

    float4 wA[8], wB[8];
    float hA[32], hB[32];

    #define LOADW(dst, kcv)                                                   \
        do {                                                                  \
            _Pragma("unroll")                                                 \
            for (int kk = 0; kk < 8; ++kk)                                    \
                dst[kk] = *reinterpret_cast<const float4*>(                   \
                    wp + (size_t)((kcv) + kk) * H_);                          \
        } while (0)

    #define LOADH(dst, kcv)                                                   \
        do {                                                                  \
            _Pragma("unroll")                                                 \
            for (int r = 0; r < 4; ++r)                                       \
                _Pragma("unroll")                                             \
                for (int kk = 0; kk < 8; ++kk)                                \
                    dst[r * 8 + kk] = hr[r * H_ + (kcv) + kk];                \
        } while (0)

    #define COMPUTE(wv, hbuf)                                                 \
        do {                                                                  \
            _Pragma("unroll")                                                 \
            for (int kk = 0; kk < 8; ++kk) {                                  \
                const double h0 = (double)hbuf[0 * 8 + kk];                   \
                const double h1 = (double)hbuf[1 * 8 + kk];                   \
                const double h2 = (double)hbuf[2 * 8 + kk];                   \
                const double h3 = (double)hbuf[3 * 8 + kk];                   \
                const double a0 = (double)wv[kk].x;                           \
                const double a1 = (double)wv[kk].y;                           \
                const double a2 = (double)wv[kk].z;                           \
                const double a3 = (double)wv[kk].w;                           \
                acc[0][0] = fma(a0, h0, acc[0][0]);                           \
                acc[0][1] = fma(a0, h1, acc[0][1]);                           \
                acc[0][2] = fma(a0, h2, acc[0][2]);                           \
                acc[0][3] = fma(a0, h3, acc[0][3]);                           \
                acc[1][0] = fma(a1, h0, acc[1][0]);                           \
                acc[1][1] = fma(a1, h1, acc[1][1]);                           \
                acc[1][2] = fma(a1, h2, acc[1][2]);                           \
                acc[1][3] = fma(a1, h3, acc[1][3]);                           \
                acc[2][0] = fma(a2, h0, acc[2][0]);                           \
                acc[2][1] = fma(a2, h1, acc[2][1]);                           \
                acc[2][2] = fma(a2, h2, acc[2][2]);                           \
                acc[2][3] = fma(a2, h3, acc[2][3]);                           \
                acc[3][0] = fma(a3, h0, acc[3][0]);                           \
                acc[3][1] = fma(a3, h1, acc[3][1]);                           \
                acc[3][2] = fma(a3, h2, acc[3][2]);                           \
                acc[3][3] = fma(a3, h3, acc[3][3]);                           \
            }                                                                 \
        } while (0)

    LOADW(wA, 0);
    LOADH(hA, 0);
    for (int kc = 0; kc < H_; kc += 16) {
        LOADW(wB, kc + 8);
        LOADH(hB, kc + 8);
        COMPUTE(wA, hA);
        if (kc + 16 < H_) {
            LOADW(wA, kc + 16);
            LOADH(hA, kc + 16);
        }
        COMPUTE(wB, hB);
    }
    #undef LOADW
    #undef LOADH
    #undef COMPUTE

    const float4 b1v = *reinterpret_cast<const float4*>(b1 + o0);
    const float4 w2v = *reinterpret_cast<const float4*>(w2 + o0);
    double psum[4] = {0.0, 0.0, 0.0, 0.0};
    #define EPI(j, bc, wc)                                                    \
        do {                                                                  \
            const double bb = (double)bc, ww = (double)wc;                    \
            _Pragma("unroll")                                                 \
            for (int r = 0; r < 4; ++r) {                                     \
                const double u = acc[j][r] + bb;                              \
                psum[r] += ww * (u / (1.0 + exp(-u)));                        \
            }                                                                 \
        } while (0)
    EPI(0, b1v.x, w2v.x);
    EPI(1, b1v.y, w2v.y);
    EPI(2, b1v.z, w2v.z);
    EPI(3, b1v.w, w2v.w);
    #undef EPI

    #pragma unroll
    for (int r = 0; r < 4; ++r) {
        double v = psum[r];
        v += __shfl_xor(v, 1, 64);
        v += __shfl_xor(v, 2, 64);
        v += __shfl_xor(v, 4, 64);
        v += __shfl_xor(v, 8, 64);
        v += __shfl_xor(v, 16, 64);
        v += __shfl_xor(v, 32, 64);
        if (lane == 0) s_out[m0 + r] = v;
    }
}

// Kernel B: out[b,i,j] = (int32)trunc( (s[b,i] - s[b,j]) + b2 )
__global__ __launch_bounds__(256)
void pair_kernel(const double* __restrict__ s, const float* __restrict__ b2p,
                 int* __restrict__ out) {
    const double b2 = (double)b2p[0];
    const unsigned total4 = (unsigned)(B_) * (unsigned)(N_) * (unsigned)(N_) / 4u;
    const unsigned stride = gridDim.x * blockDim.x;
    for (unsigned idx = blockIdx.x * blockDim.x + threadIdx.x; idx < total4;
         idx += stride) {
        const unsigned base = idx * 4u;                 // element index, %4==0
        const unsigned bi  = base >> 22;                // / (N*N), N*N = 2^22
        const unsigned rem = base & ((1u << 22) - 1u);
        const unsigned i   = rem >> 11;                 // / N
        const unsigned j   = rem & (N_ - 1u);
        const double si = s[bi * N_ + i];
        const double* sp = s + bi * N_ + j;             // 32B aligned (j%4==0)
        const double sj0 = sp[0], sj1 = sp[1], sj2 = sp[2], sj3 = sp[3];
        int4 o;
        o.x = (int)trunc((si - sj0) + b2);
        o.y = (int)trunc((si - sj1) + b2);
        o.z = (int)trunc((si - sj2) + b2);
        o.w = (int)trunc((si - sj3) + b2);
        *reinterpret_cast<int4*>(out + base) = o;
    }
}

extern "C" void kernel_launch(void* const* d_in, const int* in_sizes, int n_in,
                              void* d_out, int out_size, void* d_ws, size_t ws_size,
                              hipStream_t stream) {
    const float* hp = (const float*)d_in[0];
    // d_in[1] = node_mask (unused), d_in[2] = n_nodes (unused)
    const float* W1 = (const float*)d_in[3];
    const float* b1 = (const float*)d_in[4];
    const float* w2 = (const float*)d_in[5];
    const float* b2 = (const float*)d_in[6];

    float*  W1T = (float*)d_ws;                                   // 256 KB
    double* s   = (double*)((char*)d_ws + 256 * 1024);            // 128 KB
    int* out = (int*)d_out;

    transpose_w1<<<H_, H_, 0, stream>>>(W1, W1T);
    s_mfma_uni<<<(B_ * N_) / 16, 256, 0, stream>>>(hp, W1T, b1, w2, s);
    s_valu_kernel<<<(B_ * N_) / 16, 256, 0, stream>>>(hp, W1T, b1, w2, s);
    pair_kernel<<<2048, 256, 0, stream>>>(s, b2, out);
}